// Round 1
// baseline (795.978 us; speedup 1.0000x reference)
//
#include <hip/hip_runtime.h>
#include <math.h>

#define NN 100000   // nodes
#define NE 600000   // edges
#define DD 128      // hidden dim
#define NB_SCAN 98  // ceil(NN/1024)

// ---------------- CSR build ----------------

__global__ __launch_bounds__(256) void k_degree(const int* __restrict__ dst,
                                                int* __restrict__ deg) {
    int e = blockIdx.x * 256 + threadIdx.x;
    if (e < NE) atomicAdd(&deg[dst[e]], 1);
}

__global__ __launch_bounds__(256) void k_scan1(const int* __restrict__ deg,
                                               int* __restrict__ bsum) {
    __shared__ int sm[256];
    int t = threadIdx.x;
    int idx = blockIdx.x * 1024 + t * 4;
    int4 v = make_int4(0, 0, 0, 0);
    if (idx + 3 < NN) v = *reinterpret_cast<const int4*>(deg + idx);
    else {
        if (idx     < NN) v.x = deg[idx];
        if (idx + 1 < NN) v.y = deg[idx + 1];
        if (idx + 2 < NN) v.z = deg[idx + 2];
        if (idx + 3 < NN) v.w = deg[idx + 3];
    }
    sm[t] = v.x + v.y + v.z + v.w;
    __syncthreads();
    for (int off = 128; off > 0; off >>= 1) {
        if (t < off) sm[t] += sm[t + off];
        __syncthreads();
    }
    if (t == 0) bsum[blockIdx.x] = sm[0];
}

__global__ __launch_bounds__(128) void k_scan2(int* __restrict__ bsum) {
    __shared__ int sm[128];
    int t = threadIdx.x;
    int v = (t < NB_SCAN) ? bsum[t] : 0;
    sm[t] = v;
    __syncthreads();
    for (int off = 1; off < 128; off <<= 1) {
        int add = (t >= off) ? sm[t - off] : 0;
        __syncthreads();
        sm[t] += add;
        __syncthreads();
    }
    if (t < NB_SCAN) bsum[t] = (t == 0) ? 0 : sm[t - 1];  // exclusive, in-place
}

__global__ __launch_bounds__(256) void k_scan3(const int* __restrict__ deg,
                                               const int* __restrict__ boff,
                                               int* __restrict__ rp,
                                               int* __restrict__ cur,
                                               float* __restrict__ inv) {
    __shared__ int sm[256];
    int t = threadIdx.x;
    int idx = blockIdx.x * 1024 + t * 4;
    int4 v = make_int4(0, 0, 0, 0);
    if (idx + 3 < NN) v = *reinterpret_cast<const int4*>(deg + idx);
    else {
        if (idx     < NN) v.x = deg[idx];
        if (idx + 1 < NN) v.y = deg[idx + 1];
        if (idx + 2 < NN) v.z = deg[idx + 2];
        if (idx + 3 < NN) v.w = deg[idx + 3];
    }
    sm[t] = v.x + v.y + v.z + v.w;
    __syncthreads();
    for (int off = 1; off < 256; off <<= 1) {
        int add = (t >= off) ? sm[t - off] : 0;
        __syncthreads();
        sm[t] += add;
        __syncthreads();
    }
    int run = boff[blockIdx.x] + ((t == 0) ? 0 : sm[t - 1]);
    if (idx     < NN) { rp[idx]   = run; cur[idx]   = run; inv[idx]   = 1.0f / (float)(v.x > 0 ? v.x : 1); run += v.x; }
    if (idx + 1 < NN) { rp[idx+1] = run; cur[idx+1] = run; inv[idx+1] = 1.0f / (float)(v.y > 0 ? v.y : 1); run += v.y; }
    if (idx + 2 < NN) { rp[idx+2] = run; cur[idx+2] = run; inv[idx+2] = 1.0f / (float)(v.z > 0 ? v.z : 1); run += v.z; }
    if (idx + 3 < NN) { rp[idx+3] = run; cur[idx+3] = run; inv[idx+3] = 1.0f / (float)(v.w > 0 ? v.w : 1); run += v.w; }
    if (blockIdx.x == 0 && t == 0) rp[NN] = NE;
}

__global__ __launch_bounds__(256) void k_scatter(const int* __restrict__ src,
                                                 const int* __restrict__ dst,
                                                 int* __restrict__ cur,
                                                 int* __restrict__ col) {
    int e = blockIdx.x * 256 + threadIdx.x;
    if (e < NE) {
        int p = atomicAdd(&cur[dst[e]], 1);
        col[p] = src[e];
    }
}

// ---------------- aggregation (mean) ----------------

// one wave per node; lane holds float2 of the 128-d row
__global__ __launch_bounds__(256) void k_gather128(const float* __restrict__ X,
                                                   const int* __restrict__ rp,
                                                   const int* __restrict__ col,
                                                   const float* __restrict__ inv,
                                                   float* __restrict__ agg) {
    int wave = threadIdx.x >> 6;
    int lane = threadIdx.x & 63;
    int n = blockIdx.x * 4 + wave;
    if (n >= NN) return;
    int beg = rp[n], end = rp[n + 1];
    float ax = 0.f, ay = 0.f;
    for (int e = beg; e < end; ++e) {
        int s = col[e];
        float2 v = *reinterpret_cast<const float2*>(X + (size_t)s * DD + lane * 2);
        ax += v.x; ay += v.y;
    }
    float iv = inv[n];
    float2 o; o.x = ax * iv; o.y = ay * iv;
    *reinterpret_cast<float2*>(agg + (size_t)n * DD + lane * 2) = o;
}

// 16-wide aggregation: 16 lanes per node
__global__ __launch_bounds__(256) void k_gather16(const float* __restrict__ X,
                                                  const int* __restrict__ rp,
                                                  const int* __restrict__ col,
                                                  const float* __restrict__ inv,
                                                  float* __restrict__ agg) {
    int tid = blockIdx.x * 256 + threadIdx.x;
    int n = tid >> 4;
    int l = tid & 15;
    if (n >= NN) return;
    int beg = rp[n], end = rp[n + 1];
    float acc = 0.f;
    for (int e = beg; e < end; ++e) {
        int s = col[e];
        acc += X[(size_t)s * 16 + l];
    }
    agg[(size_t)n * 16 + l] = acc * inv[n];
}

// ---------------- fused layer epilogue (layers 0/1) ----------------
// out[n][j] = relu( sum_k A[n][k]*Wl[j][k] + sum_k X[n][k]*Wr[j][k] + b[j] )
// 128x128 block tile, 8x8 micro-tile, K-chunks of 32 per matrix.

#define KC 32
__global__ __launch_bounds__(256) void k_epilogue(const float* __restrict__ A,
                                                  const float* __restrict__ X,
                                                  const float* __restrict__ Wl,
                                                  const float* __restrict__ Wr,
                                                  const float* __restrict__ b,
                                                  float* __restrict__ out,
                                                  int do_relu) {
    __shared__ float As[KC][132];
    __shared__ float Ws[KC][132];
    int tid = threadIdx.x;
    int tx = tid & 15;      // col group: cols tx*8 .. +8
    int ty = tid >> 4;      // row group: rows ty*8 .. +8
    int r0 = blockIdx.x * 128;

    float acc[8][8];
#pragma unroll
    for (int i = 0; i < 8; ++i)
#pragma unroll
        for (int j = 0; j < 8; ++j) acc[i][j] = 0.f;

    for (int mat = 0; mat < 2; ++mat) {
        const float* Ap = mat ? X : A;
        const float* Wp = mat ? Wr : Wl;
        for (int k0 = 0; k0 < DD; k0 += KC) {
            __syncthreads();
            // stage A chunk (128 rows x 32 k), k-major in LDS
#pragma unroll
            for (int i = 0; i < 16; ++i) {
                int flat = i * 256 + tid;
                int r = flat >> 5, k = flat & 31;
                int gr = r0 + r;
                float val = (gr < NN) ? Ap[(size_t)gr * DD + k0 + k] : 0.f;
                As[k][r] = val;
            }
            // stage W chunk (128 j x 32 k), k-major
#pragma unroll
            for (int i = 0; i < 16; ++i) {
                int flat = i * 256 + tid;
                int j = flat >> 5, k = flat & 31;
                Ws[k][j] = Wp[j * DD + k0 + k];
            }
            __syncthreads();
#pragma unroll
            for (int k = 0; k < KC; ++k) {
                float4 a0 = *reinterpret_cast<const float4*>(&As[k][ty * 8]);
                float4 a1 = *reinterpret_cast<const float4*>(&As[k][ty * 8 + 4]);
                float4 w0 = *reinterpret_cast<const float4*>(&Ws[k][tx * 8]);
                float4 w1 = *reinterpret_cast<const float4*>(&Ws[k][tx * 8 + 4]);
                float av[8] = {a0.x, a0.y, a0.z, a0.w, a1.x, a1.y, a1.z, a1.w};
                float wv[8] = {w0.x, w0.y, w0.z, w0.w, w1.x, w1.y, w1.z, w1.w};
#pragma unroll
                for (int i = 0; i < 8; ++i)
#pragma unroll
                    for (int j = 0; j < 8; ++j) acc[i][j] += av[i] * wv[j];
            }
        }
    }

    float4 b0 = *reinterpret_cast<const float4*>(b + tx * 8);
    float4 b1 = *reinterpret_cast<const float4*>(b + tx * 8 + 4);
    float bias[8] = {b0.x, b0.y, b0.z, b0.w, b1.x, b1.y, b1.z, b1.w};
#pragma unroll
    for (int i = 0; i < 8; ++i) {
        int gr = r0 + ty * 8 + i;
        if (gr >= NN) continue;
        float o[8];
#pragma unroll
        for (int j = 0; j < 8; ++j) {
            float v = acc[i][j] + bias[j];
            o[j] = do_relu ? fmaxf(v, 0.f) : v;
        }
        float* dst = out + (size_t)gr * DD + tx * 8;
        *reinterpret_cast<float4*>(dst)     = make_float4(o[0], o[1], o[2], o[3]);
        *reinterpret_cast<float4*>(dst + 4) = make_float4(o[4], o[5], o[6], o[7]);
    }
}

// ---------------- layer 2 ----------------

// hl2[n][j] = sum_k H[n][k] * Wl2[j][k]   (thread per row; W broadcast from LDS)
__global__ __launch_bounds__(256) void k_hl2(const float* __restrict__ H,
                                             const float* __restrict__ Wl2,
                                             float* __restrict__ hl2) {
    __shared__ float Ws[16][132];
    int tid = threadIdx.x;
    for (int i = tid; i < 16 * 128; i += 256) Ws[i >> 7][i & 127] = Wl2[i];
    __syncthreads();
    int n = blockIdx.x * 256 + tid;
    if (n >= NN) return;
    const float4* h4 = reinterpret_cast<const float4*>(H + (size_t)n * DD);
    float acc[16];
#pragma unroll
    for (int j = 0; j < 16; ++j) acc[j] = 0.f;
    for (int k4 = 0; k4 < 32; ++k4) {
        float4 h = h4[k4];
#pragma unroll
        for (int j = 0; j < 16; ++j) {
            float4 w = *reinterpret_cast<const float4*>(&Ws[j][k4 * 4]);
            acc[j] += h.x * w.x + h.y * w.y + h.z * w.z + h.w * w.w;
        }
    }
    float* dst = hl2 + (size_t)n * 16;
#pragma unroll
    for (int j4 = 0; j4 < 4; ++j4)
        *reinterpret_cast<float4*>(dst + j4 * 4) =
            make_float4(acc[j4 * 4], acc[j4 * 4 + 1], acc[j4 * 4 + 2], acc[j4 * 4 + 3]);
}

// out[n][:] = log_softmax( agg2[n][:] + H[n]@Wr2^T + b2 )
__global__ __launch_bounds__(256) void k_final(const float* __restrict__ H,
                                               const float* __restrict__ agg2,
                                               const float* __restrict__ Wr2,
                                               const float* __restrict__ b2,
                                               float* __restrict__ out) {
    __shared__ float Ws[16][132];
    __shared__ float bs[16];
    int tid = threadIdx.x;
    for (int i = tid; i < 16 * 128; i += 256) Ws[i >> 7][i & 127] = Wr2[i];
    if (tid < 16) bs[tid] = b2[tid];
    __syncthreads();
    int n = blockIdx.x * 256 + tid;
    if (n >= NN) return;
    const float4* h4 = reinterpret_cast<const float4*>(H + (size_t)n * DD);
    float acc[16];
#pragma unroll
    for (int j = 0; j < 16; ++j) acc[j] = 0.f;
    for (int k4 = 0; k4 < 32; ++k4) {
        float4 h = h4[k4];
#pragma unroll
        for (int j = 0; j < 16; ++j) {
            float4 w = *reinterpret_cast<const float4*>(&Ws[j][k4 * 4]);
            acc[j] += h.x * w.x + h.y * w.y + h.z * w.z + h.w * w.w;
        }
    }
    const float* a2 = agg2 + (size_t)n * 16;
    float v[16];
    float m = -1e30f;
#pragma unroll
    for (int j = 0; j < 16; ++j) {
        v[j] = acc[j] + bs[j] + a2[j];
        m = fmaxf(m, v[j]);
    }
    float s = 0.f;
#pragma unroll
    for (int j = 0; j < 16; ++j) s += expf(v[j] - m);
    float lse = m + logf(s);
    float* dst = out + (size_t)n * 16;
#pragma unroll
    for (int j4 = 0; j4 < 4; ++j4)
        *reinterpret_cast<float4*>(dst + j4 * 4) =
            make_float4(v[j4 * 4] - lse, v[j4 * 4 + 1] - lse, v[j4 * 4 + 2] - lse, v[j4 * 4 + 3] - lse);
}

// ---------------- host launcher ----------------

extern "C" void kernel_launch(void* const* d_in, const int* in_sizes, int n_in,
                              void* d_out, int out_size, void* d_ws, size_t ws_size,
                              hipStream_t stream) {
    const float* x   = (const float*)d_in[0];
    const int*   ei  = (const int*)d_in[1];
    const float* Wl0 = (const float*)d_in[2];
    const float* bl0 = (const float*)d_in[3];
    const float* Wr0 = (const float*)d_in[4];
    const float* Wl1 = (const float*)d_in[5];
    const float* bl1 = (const float*)d_in[6];
    const float* Wr1 = (const float*)d_in[7];
    const float* Wl2 = (const float*)d_in[8];
    const float* bl2 = (const float*)d_in[9];
    const float* Wr2 = (const float*)d_in[10];
    float* out = (float*)d_out;

    const int* e_src = ei;       // edge_index[0]
    const int* e_dst = ei + NE;  // edge_index[1]

    // workspace carve-out (256B aligned)
    char* ws = (char*)d_ws;
    size_t off = 0;
    auto carve = [&](size_t bytes) -> void* {
        void* p = ws + off;
        off = (off + bytes + 255) & ~(size_t)255;
        return p;
    };
    int*   deg  = (int*)carve((size_t)NN * 4);
    int*   rp   = (int*)carve((size_t)(NN + 1) * 4);
    int*   cur  = (int*)carve((size_t)NN * 4);
    int*   bsum = (int*)carve(512 * 4);
    int*   col  = (int*)carve((size_t)NE * 4);
    float* inv  = (float*)carve((size_t)NN * 4);
    float* agg  = (float*)carve((size_t)NN * DD * 4);
    float* H    = (float*)carve((size_t)NN * DD * 4);
    float* hl2  = (float*)carve((size_t)NN * 16 * 4);
    float* agg2 = (float*)carve((size_t)NN * 16 * 4);
    (void)ws_size; (void)in_sizes; (void)n_in; (void)out_size;

    // CSR build
    hipMemsetAsync(deg, 0, (size_t)NN * 4, stream);
    k_degree<<<(NE + 255) / 256, 256, 0, stream>>>(e_dst, deg);
    k_scan1<<<NB_SCAN, 256, 0, stream>>>(deg, bsum);
    k_scan2<<<1, 128, 0, stream>>>(bsum);
    k_scan3<<<NB_SCAN, 256, 0, stream>>>(deg, bsum, rp, cur, inv);
    k_scatter<<<(NE + 255) / 256, 256, 0, stream>>>(e_src, e_dst, cur, col);

    // layer 0: agg = mean-gather(x); H = relu(agg@Wl0^T + x@Wr0^T + bl0)
    k_gather128<<<NN / 4, 256, 0, stream>>>(x, rp, col, inv, agg);
    k_epilogue<<<(NN + 127) / 128, 256, 0, stream>>>(agg, x, Wl0, Wr0, bl0, H, 1);

    // layer 1 (in-place on H)
    k_gather128<<<NN / 4, 256, 0, stream>>>(H, rp, col, inv, agg);
    k_epilogue<<<(NN + 127) / 128, 256, 0, stream>>>(agg, H, Wl1, Wr1, bl1, H, 1);

    // layer 2: transform-first (16-wide gather), fused log_softmax
    k_hl2<<<(NN + 255) / 256, 256, 0, stream>>>(H, Wl2, hl2);
    k_gather16<<<(NN * 16 + 255) / 256, 256, 0, stream>>>(hl2, rp, col, inv, agg2);
    k_final<<<(NN + 255) / 256, 256, 0, stream>>>(H, agg2, Wr2, bl2, out);
}

// Round 2
// 318.583 us; speedup vs baseline: 2.4985x; 2.4985x over previous
//
#include <hip/hip_runtime.h>
#include <math.h>

#define NN 100000   // nodes
#define NE 600000   // edges
#define DD 128      // hidden dim
#define NB_SCAN 98  // ceil(NN/1024)

typedef __attribute__((ext_vector_type(8))) short bf16x8;
typedef __attribute__((ext_vector_type(4))) float f32x4;
typedef unsigned short u16;
typedef unsigned int u32;

__device__ __forceinline__ float bf2f(u32 lo16) {
    union { u32 i; float f; } v;
    v.i = lo16 << 16;
    return v.f;
}
__device__ __forceinline__ u16 f2bf(float f) {
    union { float f; u32 u; } v; v.f = f;
    u32 r = v.u + 0x7fffu + ((v.u >> 16) & 1u);  // RNE
    return (u16)(r >> 16);
}

// ---------------- CSR build ----------------

__global__ __launch_bounds__(256) void k_degree(const int* __restrict__ dst,
                                                int* __restrict__ deg) {
    int e = blockIdx.x * 256 + threadIdx.x;
    if (e < NE) atomicAdd(&deg[dst[e]], 1);
}

__global__ __launch_bounds__(256) void k_scan1(const int* __restrict__ deg,
                                               int* __restrict__ bsum) {
    __shared__ int sm[256];
    int t = threadIdx.x;
    int idx = blockIdx.x * 1024 + t * 4;
    int4 v = make_int4(0, 0, 0, 0);
    if (idx + 3 < NN) v = *reinterpret_cast<const int4*>(deg + idx);
    else {
        if (idx     < NN) v.x = deg[idx];
        if (idx + 1 < NN) v.y = deg[idx + 1];
        if (idx + 2 < NN) v.z = deg[idx + 2];
        if (idx + 3 < NN) v.w = deg[idx + 3];
    }
    sm[t] = v.x + v.y + v.z + v.w;
    __syncthreads();
    for (int off = 128; off > 0; off >>= 1) {
        if (t < off) sm[t] += sm[t + off];
        __syncthreads();
    }
    if (t == 0) bsum[blockIdx.x] = sm[0];
}

__global__ __launch_bounds__(128) void k_scan2(int* __restrict__ bsum) {
    __shared__ int sm[128];
    int t = threadIdx.x;
    int v = (t < NB_SCAN) ? bsum[t] : 0;
    sm[t] = v;
    __syncthreads();
    for (int off = 1; off < 128; off <<= 1) {
        int add = (t >= off) ? sm[t - off] : 0;
        __syncthreads();
        sm[t] += add;
        __syncthreads();
    }
    if (t < NB_SCAN) bsum[t] = (t == 0) ? 0 : sm[t - 1];  // exclusive, in-place
}

__global__ __launch_bounds__(256) void k_scan3(const int* __restrict__ deg,
                                               const int* __restrict__ boff,
                                               int* __restrict__ rp,
                                               int* __restrict__ cur,
                                               float* __restrict__ inv) {
    __shared__ int sm[256];
    int t = threadIdx.x;
    int idx = blockIdx.x * 1024 + t * 4;
    int4 v = make_int4(0, 0, 0, 0);
    if (idx + 3 < NN) v = *reinterpret_cast<const int4*>(deg + idx);
    else {
        if (idx     < NN) v.x = deg[idx];
        if (idx + 1 < NN) v.y = deg[idx + 1];
        if (idx + 2 < NN) v.z = deg[idx + 2];
        if (idx + 3 < NN) v.w = deg[idx + 3];
    }
    sm[t] = v.x + v.y + v.z + v.w;
    __syncthreads();
    for (int off = 1; off < 256; off <<= 1) {
        int add = (t >= off) ? sm[t - off] : 0;
        __syncthreads();
        sm[t] += add;
        __syncthreads();
    }
    int run = boff[blockIdx.x] + ((t == 0) ? 0 : sm[t - 1]);
    if (idx     < NN) { rp[idx]   = run; cur[idx]   = run; inv[idx]   = 1.0f / (float)(v.x > 0 ? v.x : 1); run += v.x; }
    if (idx + 1 < NN) { rp[idx+1] = run; cur[idx+1] = run; inv[idx+1] = 1.0f / (float)(v.y > 0 ? v.y : 1); run += v.y; }
    if (idx + 2 < NN) { rp[idx+2] = run; cur[idx+2] = run; inv[idx+2] = 1.0f / (float)(v.z > 0 ? v.z : 1); run += v.z; }
    if (idx + 3 < NN) { rp[idx+3] = run; cur[idx+3] = run; inv[idx+3] = 1.0f / (float)(v.w > 0 ? v.w : 1); run += v.w; }
    if (blockIdx.x == 0 && t == 0) rp[NN] = NE;
}

__global__ __launch_bounds__(256) void k_scatter(const int* __restrict__ src,
                                                 const int* __restrict__ dst,
                                                 int* __restrict__ cur,
                                                 int* __restrict__ col) {
    int e = blockIdx.x * 256 + threadIdx.x;
    if (e < NE) {
        int p = atomicAdd(&cur[dst[e]], 1);
        col[p] = src[e];
    }
}

// ---------------- dtype prep ----------------

__global__ __launch_bounds__(256) void k_cast(const float* __restrict__ x,
                                              u16* __restrict__ xb) {
    int i = blockIdx.x * 256 + threadIdx.x;  // float4 index
    if (i < NN * 32) {
        float4 v = reinterpret_cast<const float4*>(x)[i];
        ushort4 o;
        o.x = f2bf(v.x); o.y = f2bf(v.y); o.z = f2bf(v.z); o.w = f2bf(v.w);
        reinterpret_cast<ushort4*>(xb)[i] = o;
    }
}

// concat [Wl | Wr] -> Wc[j][0:128]=Wl[j], Wc[j][128:256]=Wr[j], bf16
__global__ __launch_bounds__(256) void k_prep_w(const float* __restrict__ Wl0,
                                                const float* __restrict__ Wr0,
                                                const float* __restrict__ Wl1,
                                                const float* __restrict__ Wr1,
                                                u16* __restrict__ Wc0,
                                                u16* __restrict__ Wc1) {
    int t = blockIdx.x * 256 + threadIdx.x;
    if (t < 128 * 128) {
        int j = t >> 7, k = t & 127;
        Wc0[j * 256 + k]       = f2bf(Wl0[t]);
        Wc0[j * 256 + 128 + k] = f2bf(Wr0[t]);
        Wc1[j * 256 + k]       = f2bf(Wl1[t]);
        Wc1[j * 256 + 128 + k] = f2bf(Wr1[t]);
    }
}

// ---------------- aggregation (mean), bf16 ----------------

// one wave per node; lane holds 2 bf16 of the 128-d row
__global__ __launch_bounds__(256) void k_gather128b(const u16* __restrict__ X,
                                                    const int* __restrict__ rp,
                                                    const int* __restrict__ col,
                                                    const float* __restrict__ inv,
                                                    u16* __restrict__ agg) {
    int wave = threadIdx.x >> 6;
    int lane = threadIdx.x & 63;
    int n = blockIdx.x * 4 + wave;
    if (n >= NN) return;
    int beg = rp[n], end = rp[n + 1];
    float ax = 0.f, ay = 0.f;
    int e = beg;
    for (; e + 1 < end; e += 2) {
        int s0 = col[e], s1 = col[e + 1];
        u32 v0 = *reinterpret_cast<const u32*>(X + (size_t)s0 * DD + lane * 2);
        u32 v1 = *reinterpret_cast<const u32*>(X + (size_t)s1 * DD + lane * 2);
        ax += bf2f(v0 & 0xffffu) + bf2f(v1 & 0xffffu);
        ay += bf2f(v0 >> 16)     + bf2f(v1 >> 16);
    }
    if (e < end) {
        u32 v0 = *reinterpret_cast<const u32*>(X + (size_t)col[e] * DD + lane * 2);
        ax += bf2f(v0 & 0xffffu);
        ay += bf2f(v0 >> 16);
    }
    float iv = inv[n];
    u32 o = ((u32)f2bf(ay * iv) << 16) | (u32)f2bf(ax * iv);
    *reinterpret_cast<u32*>(agg + (size_t)n * DD + lane * 2) = o;
}

// 16-wide aggregation on fp32 (layer-2 transformed features)
__global__ __launch_bounds__(256) void k_gather16(const float* __restrict__ X,
                                                  const int* __restrict__ rp,
                                                  const int* __restrict__ col,
                                                  const float* __restrict__ inv,
                                                  float* __restrict__ agg) {
    int tid = blockIdx.x * 256 + threadIdx.x;
    int n = tid >> 4;
    int l = tid & 15;
    if (n >= NN) return;
    int beg = rp[n], end = rp[n + 1];
    float acc = 0.f;
    for (int e = beg; e < end; ++e) {
        int s = col[e];
        acc += X[(size_t)s * 16 + l];
    }
    agg[(size_t)n * 16 + l] = acc * inv[n];
}

// ---------------- MFMA fused epilogue (layers 0/1) ----------------
// out[n][j] = relu( [A0|A1][n][:] . Wc[j][:] + b[j] ),  K = 256, bf16 MFMA.
// 128x128 tile, 4 waves (2x2), each wave 64x64 = 4x4 frags of 16x16x32.
// LDS XOR-swizzle: byte_in_row ^= (row&7)<<4  (conflict-free b128 stage+read).

__global__ __launch_bounds__(256) void k_mfma_epi(const u16* __restrict__ A0,
                                                  const u16* __restrict__ A1,
                                                  const u16* __restrict__ Wc,
                                                  const float* __restrict__ b,
                                                  u16* __restrict__ out,
                                                  int do_relu) {
    __shared__ u16 As[128 * 64];
    __shared__ u16 Bs[128 * 64];
    int tid = threadIdx.x;
    int wid = tid >> 6, lane = tid & 63;
    int wm = wid >> 1, wn = wid & 1;
    int r0 = blockIdx.x * 128;

    f32x4 acc[4][4];
#pragma unroll
    for (int i = 0; i < 4; ++i)
#pragma unroll
        for (int j = 0; j < 4; ++j) acc[i][j] = (f32x4){0.f, 0.f, 0.f, 0.f};

    for (int kc = 0; kc < 4; ++kc) {          // 4 K-chunks of 64 (A0:0-127, A1:128-255)
        const u16* Ap = (kc < 2) ? A0 : A1;
        int kco = (kc & 1) * 64;
        __syncthreads();
        // stage A chunk: 128 rows x 64 bf16 (128 B/row), swizzled
#pragma unroll
        for (int p = 0; p < 4; ++p) {
            int flat = p * 256 + tid;          // 0..1023
            int r  = flat >> 3;                // 0..127
            int bq = flat & 7;                 // 16B unit in row
            int gr = r0 + r;
            uint4 v = make_uint4(0, 0, 0, 0);
            if (gr < NN) v = *reinterpret_cast<const uint4*>(Ap + (size_t)gr * DD + kco + bq * 8);
            int sb = r * 128 + ((bq * 16) ^ ((r & 7) << 4));
            *reinterpret_cast<uint4*>(reinterpret_cast<char*>(As) + sb) = v;
        }
        // stage B chunk: Wc rows j=0..127, cols kc*64..+63 (stride 256)
#pragma unroll
        for (int p = 0; p < 4; ++p) {
            int flat = p * 256 + tid;
            int j  = flat >> 3;
            int bq = flat & 7;
            uint4 v = *reinterpret_cast<const uint4*>(Wc + (size_t)j * 256 + kc * 64 + bq * 8);
            int sb = j * 128 + ((bq * 16) ^ ((j & 7) << 4));
            *reinterpret_cast<uint4*>(reinterpret_cast<char*>(Bs) + sb) = v;
        }
        __syncthreads();
#pragma unroll
        for (int ks = 0; ks < 2; ++ks) {       // 2 MFMA K-steps of 32
            int kb = ks * 64 + ((lane >> 4) * 16);  // byte offset pre-swizzle
            bf16x8 af[4], bf[4];
#pragma unroll
            for (int mf = 0; mf < 4; ++mf) {
                int row = wm * 64 + mf * 16 + (lane & 15);
                int sb = row * 128 + (kb ^ ((row & 7) << 4));
                af[mf] = *reinterpret_cast<const bf16x8*>(reinterpret_cast<const char*>(As) + sb);
            }
#pragma unroll
            for (int nf = 0; nf < 4; ++nf) {
                int row = wn * 64 + nf * 16 + (lane & 15);
                int sb = row * 128 + (kb ^ ((row & 7) << 4));
                bf[nf] = *reinterpret_cast<const bf16x8*>(reinterpret_cast<const char*>(Bs) + sb);
            }
#pragma unroll
            for (int mf = 0; mf < 4; ++mf)
#pragma unroll
                for (int nf = 0; nf < 4; ++nf)
                    acc[mf][nf] = __builtin_amdgcn_mfma_f32_16x16x32_bf16(af[mf], bf[nf], acc[mf][nf], 0, 0, 0);
        }
    }

    // epilogue: bias + relu + bf16 store
    int cl = lane & 15, rq = lane >> 4;
#pragma unroll
    for (int nf = 0; nf < 4; ++nf) {
        int colj = wn * 64 + nf * 16 + cl;
        float bias = b[colj];
#pragma unroll
        for (int mf = 0; mf < 4; ++mf) {
            int row = r0 + wm * 64 + mf * 16 + rq * 4;
#pragma unroll
            for (int v = 0; v < 4; ++v) {
                if (row + v < NN) {
                    float o = acc[mf][nf][v] + bias;
                    if (do_relu) o = fmaxf(o, 0.f);
                    out[(size_t)(row + v) * DD + colj] = f2bf(o);
                }
            }
        }
    }
}

// ---------------- layer 2 ----------------

// hl2[n][j] = sum_k H[n][k] * Wl2[j][k]   (H bf16, W fp32 in LDS)
__global__ __launch_bounds__(256) void k_hl2(const u16* __restrict__ H,
                                             const float* __restrict__ Wl2,
                                             float* __restrict__ hl2) {
    __shared__ float Ws[16][128];
    int tid = threadIdx.x;
    for (int i = tid; i < 16 * 128; i += 256) Ws[i >> 7][i & 127] = Wl2[i];
    __syncthreads();
    int n = blockIdx.x * 256 + tid;
    if (n >= NN) return;
    const uint4* h4 = reinterpret_cast<const uint4*>(H + (size_t)n * DD);
    float acc[16];
#pragma unroll
    for (int j = 0; j < 16; ++j) acc[j] = 0.f;
    for (int c = 0; c < 16; ++c) {             // 8 bf16 per chunk
        uint4 hv = h4[c];
        float hf[8] = {bf2f(hv.x & 0xffffu), bf2f(hv.x >> 16),
                       bf2f(hv.y & 0xffffu), bf2f(hv.y >> 16),
                       bf2f(hv.z & 0xffffu), bf2f(hv.z >> 16),
                       bf2f(hv.w & 0xffffu), bf2f(hv.w >> 16)};
#pragma unroll
        for (int j = 0; j < 16; ++j) {
            const float4* w4 = reinterpret_cast<const float4*>(&Ws[j][c * 8]);
            float4 w0 = w4[0], w1 = w4[1];
            acc[j] += hf[0] * w0.x + hf[1] * w0.y + hf[2] * w0.z + hf[3] * w0.w
                    + hf[4] * w1.x + hf[5] * w1.y + hf[6] * w1.z + hf[7] * w1.w;
        }
    }
    float* dst = hl2 + (size_t)n * 16;
#pragma unroll
    for (int j4 = 0; j4 < 4; ++j4)
        *reinterpret_cast<float4*>(dst + j4 * 4) =
            make_float4(acc[j4 * 4], acc[j4 * 4 + 1], acc[j4 * 4 + 2], acc[j4 * 4 + 3]);
}

// out[n][:] = log_softmax( agg2[n][:] + H[n]@Wr2^T + b2 )
__global__ __launch_bounds__(256) void k_final(const u16* __restrict__ H,
                                               const float* __restrict__ agg2,
                                               const float* __restrict__ Wr2,
                                               const float* __restrict__ b2,
                                               float* __restrict__ out) {
    __shared__ float Ws[16][128];
    __shared__ float bs[16];
    int tid = threadIdx.x;
    for (int i = tid; i < 16 * 128; i += 256) Ws[i >> 7][i & 127] = Wr2[i];
    if (tid < 16) bs[tid] = b2[tid];
    __syncthreads();
    int n = blockIdx.x * 256 + tid;
    if (n >= NN) return;
    const uint4* h4 = reinterpret_cast<const uint4*>(H + (size_t)n * DD);
    float acc[16];
#pragma unroll
    for (int j = 0; j < 16; ++j) acc[j] = 0.f;
    for (int c = 0; c < 16; ++c) {
        uint4 hv = h4[c];
        float hf[8] = {bf2f(hv.x & 0xffffu), bf2f(hv.x >> 16),
                       bf2f(hv.y & 0xffffu), bf2f(hv.y >> 16),
                       bf2f(hv.z & 0xffffu), bf2f(hv.z >> 16),
                       bf2f(hv.w & 0xffffu), bf2f(hv.w >> 16)};
#pragma unroll
        for (int j = 0; j < 16; ++j) {
            const float4* w4 = reinterpret_cast<const float4*>(&Ws[j][c * 8]);
            float4 w0 = w4[0], w1 = w4[1];
            acc[j] += hf[0] * w0.x + hf[1] * w0.y + hf[2] * w0.z + hf[3] * w0.w
                    + hf[4] * w1.x + hf[5] * w1.y + hf[6] * w1.z + hf[7] * w1.w;
        }
    }
    const float* a2 = agg2 + (size_t)n * 16;
    float v[16];
    float m = -1e30f;
#pragma unroll
    for (int j = 0; j < 16; ++j) {
        v[j] = acc[j] + bs[j] + a2[j];
        m = fmaxf(m, v[j]);
    }
    float s = 0.f;
#pragma unroll
    for (int j = 0; j < 16; ++j) s += expf(v[j] - m);
    float lse = m + logf(s);
    float* dst = out + (size_t)n * 16;
#pragma unroll
    for (int j4 = 0; j4 < 4; ++j4)
        *reinterpret_cast<float4*>(dst + j4 * 4) =
            make_float4(v[j4 * 4] - lse, v[j4 * 4 + 1] - lse, v[j4 * 4 + 2] - lse, v[j4 * 4 + 3] - lse);
}

// ---------------- host launcher ----------------

extern "C" void kernel_launch(void* const* d_in, const int* in_sizes, int n_in,
                              void* d_out, int out_size, void* d_ws, size_t ws_size,
                              hipStream_t stream) {
    const float* x   = (const float*)d_in[0];
    const int*   ei  = (const int*)d_in[1];
    const float* Wl0 = (const float*)d_in[2];
    const float* bl0 = (const float*)d_in[3];
    const float* Wr0 = (const float*)d_in[4];
    const float* Wl1 = (const float*)d_in[5];
    const float* bl1 = (const float*)d_in[6];
    const float* Wr1 = (const float*)d_in[7];
    const float* Wl2 = (const float*)d_in[8];
    const float* bl2 = (const float*)d_in[9];
    const float* Wr2 = (const float*)d_in[10];
    float* out = (float*)d_out;

    const int* e_src = ei;       // edge_index[0]
    const int* e_dst = ei + NE;  // edge_index[1]

    // workspace carve-out (256B aligned)
    char* ws = (char*)d_ws;
    size_t off = 0;
    auto carve = [&](size_t bytes) -> void* {
        void* p = ws + off;
        off = (off + bytes + 255) & ~(size_t)255;
        return p;
    };
    int*   deg  = (int*)carve((size_t)NN * 4);
    int*   rp   = (int*)carve((size_t)(NN + 1) * 4);
    int*   cur  = (int*)carve((size_t)NN * 4);
    int*   bsum = (int*)carve(512 * 4);
    int*   col  = (int*)carve((size_t)NE * 4);
    float* inv  = (float*)carve((size_t)NN * 4);
    u16*   xb   = (u16*)carve((size_t)NN * DD * 2);
    u16*   aggb = (u16*)carve((size_t)NN * DD * 2);
    u16*   Hb   = (u16*)carve((size_t)NN * DD * 2);
    u16*   Wc0  = (u16*)carve((size_t)128 * 256 * 2);
    u16*   Wc1  = (u16*)carve((size_t)128 * 256 * 2);
    float* hl2  = (float*)carve((size_t)NN * 16 * 4);
    float* agg2 = (float*)carve((size_t)NN * 16 * 4);
    (void)ws_size; (void)in_sizes; (void)n_in; (void)out_size;

    // dtype prep
    k_cast<<<(NN * 32 + 255) / 256, 256, 0, stream>>>(x, xb);
    k_prep_w<<<64, 256, 0, stream>>>(Wl0, Wr0, Wl1, Wr1, Wc0, Wc1);

    // CSR build
    hipMemsetAsync(deg, 0, (size_t)NN * 4, stream);
    k_degree<<<(NE + 255) / 256, 256, 0, stream>>>(e_dst, deg);
    k_scan1<<<NB_SCAN, 256, 0, stream>>>(deg, bsum);
    k_scan2<<<1, 128, 0, stream>>>(bsum);
    k_scan3<<<NB_SCAN, 256, 0, stream>>>(deg, bsum, rp, cur, inv);
    k_scatter<<<(NE + 255) / 256, 256, 0, stream>>>(e_src, e_dst, cur, col);

    const int nblk = (NN + 127) / 128;  // 782

    // layer 0: aggb = mean-gather(xb); Hb = relu([aggb|xb]@Wc0 + bl0)
    k_gather128b<<<NN / 4, 256, 0, stream>>>(xb, rp, col, inv, aggb);
    k_mfma_epi<<<nblk, 256, 0, stream>>>(aggb, xb, Wc0, bl0, Hb, 1);

    // layer 1 (in-place on Hb: each block reads exactly the rows it writes)
    k_gather128b<<<NN / 4, 256, 0, stream>>>(Hb, rp, col, inv, aggb);
    k_mfma_epi<<<nblk, 256, 0, stream>>>(aggb, Hb, Wc1, bl1, Hb, 1);

    // layer 2: transform-first (16-wide gather), fused log_softmax
    k_hl2<<<(NN + 255) / 256, 256, 0, stream>>>(Hb, Wl2, hl2);
    k_gather16<<<(NN * 16 + 255) / 256, 256, 0, stream>>>(hl2, rp, col, inv, agg2);
    k_final<<<(NN + 255) / 256, 256, 0, stream>>>(Hb, agg2, Wr2, bl2, out);
}

// Round 3
// 249.427 us; speedup vs baseline: 3.1912x; 1.2773x over previous
//
#include <hip/hip_runtime.h>
#include <math.h>

#define NN 100000   // nodes
#define NE 600000   // edges
#define DD 128      // hidden dim
#define NB_SCAN 98  // ceil(NN/1024)

typedef __attribute__((ext_vector_type(8))) short bf16x8;
typedef __attribute__((ext_vector_type(4))) float f32x4;
typedef unsigned short u16;
typedef unsigned int u32;

__device__ __forceinline__ float bflo(u32 w) {
    union { u32 i; float f; } v; v.i = w << 16; return v.f;
}
__device__ __forceinline__ float bfhi(u32 w) {
    union { u32 i; float f; } v; v.i = w & 0xffff0000u; return v.f;
}
__device__ __forceinline__ u16 f2bf(float f) {
    union { float f; u32 u; } v; v.f = f;
    u32 r = v.u + 0x7fffu + ((v.u >> 16) & 1u);  // RNE
    return (u16)(r >> 16);
}

// ---------------- CSR build ----------------

__global__ __launch_bounds__(256) void k_degree(const int* __restrict__ dst,
                                                int* __restrict__ deg) {
    int e = blockIdx.x * 256 + threadIdx.x;
    if (e < NE) atomicAdd(&deg[dst[e]], 1);
}

__global__ __launch_bounds__(256) void k_scan1(const int* __restrict__ deg,
                                               int* __restrict__ bsum) {
    __shared__ int sm[256];
    int t = threadIdx.x;
    int idx = blockIdx.x * 1024 + t * 4;
    int4 v = make_int4(0, 0, 0, 0);
    if (idx + 3 < NN) v = *reinterpret_cast<const int4*>(deg + idx);
    else {
        if (idx     < NN) v.x = deg[idx];
        if (idx + 1 < NN) v.y = deg[idx + 1];
        if (idx + 2 < NN) v.z = deg[idx + 2];
        if (idx + 3 < NN) v.w = deg[idx + 3];
    }
    sm[t] = v.x + v.y + v.z + v.w;
    __syncthreads();
    for (int off = 128; off > 0; off >>= 1) {
        if (t < off) sm[t] += sm[t + off];
        __syncthreads();
    }
    if (t == 0) bsum[blockIdx.x] = sm[0];
}

__global__ __launch_bounds__(128) void k_scan2(int* __restrict__ bsum) {
    __shared__ int sm[128];
    int t = threadIdx.x;
    int v = (t < NB_SCAN) ? bsum[t] : 0;
    sm[t] = v;
    __syncthreads();
    for (int off = 1; off < 128; off <<= 1) {
        int add = (t >= off) ? sm[t - off] : 0;
        __syncthreads();
        sm[t] += add;
        __syncthreads();
    }
    if (t < NB_SCAN) bsum[t] = (t == 0) ? 0 : sm[t - 1];  // exclusive, in-place
}

__global__ __launch_bounds__(256) void k_scan3(const int* __restrict__ deg,
                                               const int* __restrict__ boff,
                                               int* __restrict__ rp,
                                               int* __restrict__ cur,
                                               float* __restrict__ inv) {
    __shared__ int sm[256];
    int t = threadIdx.x;
    int idx = blockIdx.x * 1024 + t * 4;
    int4 v = make_int4(0, 0, 0, 0);
    if (idx + 3 < NN) v = *reinterpret_cast<const int4*>(deg + idx);
    else {
        if (idx     < NN) v.x = deg[idx];
        if (idx + 1 < NN) v.y = deg[idx + 1];
        if (idx + 2 < NN) v.z = deg[idx + 2];
        if (idx + 3 < NN) v.w = deg[idx + 3];
    }
    sm[t] = v.x + v.y + v.z + v.w;
    __syncthreads();
    for (int off = 1; off < 256; off <<= 1) {
        int add = (t >= off) ? sm[t - off] : 0;
        __syncthreads();
        sm[t] += add;
        __syncthreads();
    }
    int run = boff[blockIdx.x] + ((t == 0) ? 0 : sm[t - 1]);
    if (idx     < NN) { rp[idx]   = run; cur[idx]   = run; inv[idx]   = 1.0f / (float)(v.x > 0 ? v.x : 1); run += v.x; }
    if (idx + 1 < NN) { rp[idx+1] = run; cur[idx+1] = run; inv[idx+1] = 1.0f / (float)(v.y > 0 ? v.y : 1); run += v.y; }
    if (idx + 2 < NN) { rp[idx+2] = run; cur[idx+2] = run; inv[idx+2] = 1.0f / (float)(v.z > 0 ? v.z : 1); run += v.z; }
    if (idx + 3 < NN) { rp[idx+3] = run; cur[idx+3] = run; inv[idx+3] = 1.0f / (float)(v.w > 0 ? v.w : 1); run += v.w; }
    if (blockIdx.x == 0 && t == 0) rp[NN] = NE;
}

__global__ __launch_bounds__(256) void k_scatter(const int* __restrict__ src,
                                                 const int* __restrict__ dst,
                                                 int* __restrict__ cur,
                                                 int* __restrict__ col) {
    int e = blockIdx.x * 256 + threadIdx.x;
    if (e < NE) {
        int p = atomicAdd(&cur[dst[e]], 1);
        col[p] = src[e];
    }
}

// ---------------- dtype prep ----------------

__global__ __launch_bounds__(256) void k_cast(const float* __restrict__ x,
                                              u16* __restrict__ xb) {
    int i = blockIdx.x * 256 + threadIdx.x;  // float4 index
    if (i < NN * 32) {
        float4 v = reinterpret_cast<const float4*>(x)[i];
        ushort4 o;
        o.x = f2bf(v.x); o.y = f2bf(v.y); o.z = f2bf(v.z); o.w = f2bf(v.w);
        reinterpret_cast<ushort4*>(xb)[i] = o;
    }
}

// concat [Wl | Wr] -> Wc[j][0:128]=Wl[j], Wc[j][128:256]=Wr[j], bf16
__global__ __launch_bounds__(256) void k_prep_w(const float* __restrict__ Wl0,
                                                const float* __restrict__ Wr0,
                                                const float* __restrict__ Wl1,
                                                const float* __restrict__ Wr1,
                                                u16* __restrict__ Wc0,
                                                u16* __restrict__ Wc1) {
    int t = blockIdx.x * 256 + threadIdx.x;
    if (t < 128 * 128) {
        int j = t >> 7, k = t & 127;
        Wc0[j * 256 + k]       = f2bf(Wl0[t]);
        Wc0[j * 256 + 128 + k] = f2bf(Wr0[t]);
        Wc1[j * 256 + k]       = f2bf(Wl1[t]);
        Wc1[j * 256 + 128 + k] = f2bf(Wr1[t]);
    }
}

// ---------------- aggregation (mean), bf16 ----------------
// 16 lanes per node; lane holds 16B (8 bf16) of the 256B row.
// grid = NN/16 blocks of 256 threads (exact: 100000 = 6250*16).

__global__ __launch_bounds__(256) void k_gather128b(const u16* __restrict__ X,
                                                    const int* __restrict__ rp,
                                                    const int* __restrict__ col,
                                                    const float* __restrict__ inv,
                                                    u16* __restrict__ agg) {
    int tid = blockIdx.x * 256 + threadIdx.x;
    int n = tid >> 4;
    int sl = tid & 15;
    int beg = rp[n], end = rp[n + 1];
    float a0 = 0.f, a1 = 0.f, a2 = 0.f, a3 = 0.f, a4 = 0.f, a5 = 0.f, a6 = 0.f, a7 = 0.f;
    int e = beg;
    for (; e + 1 < end; e += 2) {
        int s0 = col[e], s1 = col[e + 1];
        uint4 v0 = *reinterpret_cast<const uint4*>(X + (size_t)s0 * DD + sl * 8);
        uint4 v1 = *reinterpret_cast<const uint4*>(X + (size_t)s1 * DD + sl * 8);
        a0 += bflo(v0.x) + bflo(v1.x); a1 += bfhi(v0.x) + bfhi(v1.x);
        a2 += bflo(v0.y) + bflo(v1.y); a3 += bfhi(v0.y) + bfhi(v1.y);
        a4 += bflo(v0.z) + bflo(v1.z); a5 += bfhi(v0.z) + bfhi(v1.z);
        a6 += bflo(v0.w) + bflo(v1.w); a7 += bfhi(v0.w) + bfhi(v1.w);
    }
    if (e < end) {
        uint4 v0 = *reinterpret_cast<const uint4*>(X + (size_t)col[e] * DD + sl * 8);
        a0 += bflo(v0.x); a1 += bfhi(v0.x);
        a2 += bflo(v0.y); a3 += bfhi(v0.y);
        a4 += bflo(v0.z); a5 += bfhi(v0.z);
        a6 += bflo(v0.w); a7 += bfhi(v0.w);
    }
    float iv = inv[n];
    uint4 o;
    o.x = (u32)f2bf(a0 * iv) | ((u32)f2bf(a1 * iv) << 16);
    o.y = (u32)f2bf(a2 * iv) | ((u32)f2bf(a3 * iv) << 16);
    o.z = (u32)f2bf(a4 * iv) | ((u32)f2bf(a5 * iv) << 16);
    o.w = (u32)f2bf(a6 * iv) | ((u32)f2bf(a7 * iv) << 16);
    *reinterpret_cast<uint4*>(agg + (size_t)n * DD + sl * 8) = o;
}

// 16-wide aggregation on fp32 (layer-2 transformed features)
__global__ __launch_bounds__(256) void k_gather16(const float* __restrict__ X,
                                                  const int* __restrict__ rp,
                                                  const int* __restrict__ col,
                                                  const float* __restrict__ inv,
                                                  float* __restrict__ agg) {
    int tid = blockIdx.x * 256 + threadIdx.x;
    int n = tid >> 4;
    int l = tid & 15;
    if (n >= NN) return;
    int beg = rp[n], end = rp[n + 1];
    float acc = 0.f;
    for (int e = beg; e < end; ++e) {
        int s = col[e];
        acc += X[(size_t)s * 16 + l];
    }
    agg[(size_t)n * 16 + l] = acc * inv[n];
}

// ---------------- MFMA fused epilogue (layers 0/1) ----------------
// out[n][j] = relu( [A0|A1][n][:] . Wc[j][:] + b[j] ),  K = 256, bf16 MFMA.
// W (128x256) staged ONCE to LDS (XOR-swizzled), then each wave independently
// computes 32 nodes x 128 cols with A-operand = W rows (LDS), B-operand =
// node rows streamed global->register. No barriers in the main loop.
// Swapped operands: D row = W-row j, D col = node n  -> lane holds 4
// consecutive j for one n -> packed 8B stores (write-combine friendly).

__global__ __launch_bounds__(256) void k_mfma_epi(const u16* __restrict__ A0,
                                                  const u16* __restrict__ A1,
                                                  const u16* __restrict__ Wc,
                                                  const float* __restrict__ b,
                                                  u16* __restrict__ out,
                                                  int do_relu) {
    __shared__ u16 Ws[128 * 256];  // 64 KB, swizzled: byte_in_row ^= (j&7)<<4
    int tid = threadIdx.x;
#pragma unroll
    for (int p = 0; p < 16; ++p) {
        int flat = p * 256 + tid;       // uint4 units, 0..4095
        int j = flat >> 5, q = flat & 31;
        uint4 v = *reinterpret_cast<const uint4*>(Wc + (size_t)j * 256 + q * 8);
        int sb = j * 512 + ((q * 16) ^ ((j & 7) << 4));
        *reinterpret_cast<uint4*>(reinterpret_cast<char*>(Ws) + sb) = v;
    }
    __syncthreads();

    int wid = tid >> 6, lane = tid & 63;
    int n0 = blockIdx.x * 128 + wid * 32;
    if (n0 >= NN) return;
    int cl = lane & 15, rq = lane >> 4;

    f32x4 acc[2][8];
#pragma unroll
    for (int f = 0; f < 2; ++f)
#pragma unroll
        for (int jf = 0; jf < 8; ++jf) acc[f][jf] = (f32x4){0.f, 0.f, 0.f, 0.f};

    for (int half = 0; half < 2; ++half) {
        const u16* Ap = half ? A1 : A0;
        const u16* r0p = Ap + (size_t)(n0 + cl) * DD + rq * 8;
        const u16* r1p = Ap + (size_t)(n0 + 16 + cl) * DD + rq * 8;
#pragma unroll 2
        for (int ks = 0; ks < 4; ++ks) {
            bf16x8 x0 = *reinterpret_cast<const bf16x8*>(r0p + ks * 32);
            bf16x8 x1 = *reinterpret_cast<const bf16x8*>(r1p + ks * 32);
            int kb = (half * 4 + ks) * 64 + rq * 16;   // byte offset in W row
#pragma unroll
            for (int jf = 0; jf < 8; ++jf) {
                int j = jf * 16 + cl;
                int sb = j * 512 + (kb ^ ((j & 7) << 4));
                bf16x8 wf = *reinterpret_cast<const bf16x8*>(reinterpret_cast<const char*>(Ws) + sb);
                acc[0][jf] = __builtin_amdgcn_mfma_f32_16x16x32_bf16(wf, x0, acc[0][jf], 0, 0, 0);
                acc[1][jf] = __builtin_amdgcn_mfma_f32_16x16x32_bf16(wf, x1, acc[1][jf], 0, 0, 0);
            }
        }
    }

    // epilogue: bias + relu + packed bf16x4 (8B) stores
#pragma unroll
    for (int jf = 0; jf < 8; ++jf) {
        float4 bias = *reinterpret_cast<const float4*>(b + jf * 16 + rq * 4);
#pragma unroll
        for (int f = 0; f < 2; ++f) {
            int n = n0 + f * 16 + cl;
            float o0 = acc[f][jf][0] + bias.x;
            float o1 = acc[f][jf][1] + bias.y;
            float o2 = acc[f][jf][2] + bias.z;
            float o3 = acc[f][jf][3] + bias.w;
            if (do_relu) {
                o0 = fmaxf(o0, 0.f); o1 = fmaxf(o1, 0.f);
                o2 = fmaxf(o2, 0.f); o3 = fmaxf(o3, 0.f);
            }
            uint2 pk;
            pk.x = (u32)f2bf(o0) | ((u32)f2bf(o1) << 16);
            pk.y = (u32)f2bf(o2) | ((u32)f2bf(o3) << 16);
            *reinterpret_cast<uint2*>(out + (size_t)n * DD + jf * 16 + rq * 4) = pk;
        }
    }
}

// ---------------- layer 2 ----------------

// hl2[n][j] = sum_k H[n][k] * Wl2[j][k]   (H bf16, W fp32 in LDS)
__global__ __launch_bounds__(256) void k_hl2(const u16* __restrict__ H,
                                             const float* __restrict__ Wl2,
                                             float* __restrict__ hl2) {
    __shared__ float Ws[16][128];
    int tid = threadIdx.x;
    for (int i = tid; i < 16 * 128; i += 256) Ws[i >> 7][i & 127] = Wl2[i];
    __syncthreads();
    int n = blockIdx.x * 256 + tid;
    if (n >= NN) return;
    const uint4* h4 = reinterpret_cast<const uint4*>(H + (size_t)n * DD);
    float acc[16];
#pragma unroll
    for (int j = 0; j < 16; ++j) acc[j] = 0.f;
    for (int c = 0; c < 16; ++c) {             // 8 bf16 per chunk
        uint4 hv = h4[c];
        float hf[8] = {bflo(hv.x), bfhi(hv.x), bflo(hv.y), bfhi(hv.y),
                       bflo(hv.z), bfhi(hv.z), bflo(hv.w), bfhi(hv.w)};
#pragma unroll
        for (int j = 0; j < 16; ++j) {
            const float4* w4 = reinterpret_cast<const float4*>(&Ws[j][c * 8]);
            float4 w0 = w4[0], w1 = w4[1];
            acc[j] += hf[0] * w0.x + hf[1] * w0.y + hf[2] * w0.z + hf[3] * w0.w
                    + hf[4] * w1.x + hf[5] * w1.y + hf[6] * w1.z + hf[7] * w1.w;
        }
    }
    float* dst = hl2 + (size_t)n * 16;
#pragma unroll
    for (int j4 = 0; j4 < 4; ++j4)
        *reinterpret_cast<float4*>(dst + j4 * 4) =
            make_float4(acc[j4 * 4], acc[j4 * 4 + 1], acc[j4 * 4 + 2], acc[j4 * 4 + 3]);
}

// out[n][:] = log_softmax( agg2[n][:] + H[n]@Wr2^T + b2 )
__global__ __launch_bounds__(256) void k_final(const u16* __restrict__ H,
                                               const float* __restrict__ agg2,
                                               const float* __restrict__ Wr2,
                                               const float* __restrict__ b2,
                                               float* __restrict__ out) {
    __shared__ float Ws[16][128];
    __shared__ float bs[16];
    int tid = threadIdx.x;
    for (int i = tid; i < 16 * 128; i += 256) Ws[i >> 7][i & 127] = Wr2[i];
    if (tid < 16) bs[tid] = b2[tid];
    __syncthreads();
    int n = blockIdx.x * 256 + tid;
    if (n >= NN) return;
    const uint4* h4 = reinterpret_cast<const uint4*>(H + (size_t)n * DD);
    float acc[16];
#pragma unroll
    for (int j = 0; j < 16; ++j) acc[j] = 0.f;
    for (int c = 0; c < 16; ++c) {
        uint4 hv = h4[c];
        float hf[8] = {bflo(hv.x), bfhi(hv.x), bflo(hv.y), bfhi(hv.y),
                       bflo(hv.z), bfhi(hv.z), bflo(hv.w), bfhi(hv.w)};
#pragma unroll
        for (int j = 0; j < 16; ++j) {
            const float4* w4 = reinterpret_cast<const float4*>(&Ws[j][c * 8]);
            float4 w0 = w4[0], w1 = w4[1];
            acc[j] += hf[0] * w0.x + hf[1] * w0.y + hf[2] * w0.z + hf[3] * w0.w
                    + hf[4] * w1.x + hf[5] * w1.y + hf[6] * w1.z + hf[7] * w1.w;
        }
    }
    const float* a2 = agg2 + (size_t)n * 16;
    float v[16];
    float m = -1e30f;
#pragma unroll
    for (int j = 0; j < 16; ++j) {
        v[j] = acc[j] + bs[j] + a2[j];
        m = fmaxf(m, v[j]);
    }
    float s = 0.f;
#pragma unroll
    for (int j = 0; j < 16; ++j) s += expf(v[j] - m);
    float lse = m + logf(s);
    float* dst = out + (size_t)n * 16;
#pragma unroll
    for (int j4 = 0; j4 < 4; ++j4)
        *reinterpret_cast<float4*>(dst + j4 * 4) =
            make_float4(v[j4 * 4] - lse, v[j4 * 4 + 1] - lse, v[j4 * 4 + 2] - lse, v[j4 * 4 + 3] - lse);
}

// ---------------- host launcher ----------------

extern "C" void kernel_launch(void* const* d_in, const int* in_sizes, int n_in,
                              void* d_out, int out_size, void* d_ws, size_t ws_size,
                              hipStream_t stream) {
    const float* x   = (const float*)d_in[0];
    const int*   ei  = (const int*)d_in[1];
    const float* Wl0 = (const float*)d_in[2];
    const float* bl0 = (const float*)d_in[3];
    const float* Wr0 = (const float*)d_in[4];
    const float* Wl1 = (const float*)d_in[5];
    const float* bl1 = (const float*)d_in[6];
    const float* Wr1 = (const float*)d_in[7];
    const float* Wl2 = (const float*)d_in[8];
    const float* bl2 = (const float*)d_in[9];
    const float* Wr2 = (const float*)d_in[10];
    float* out = (float*)d_out;

    const int* e_src = ei;       // edge_index[0]
    const int* e_dst = ei + NE;  // edge_index[1]

    // workspace carve-out (256B aligned)
    char* ws = (char*)d_ws;
    size_t off = 0;
    auto carve = [&](size_t bytes) -> void* {
        void* p = ws + off;
        off = (off + bytes + 255) & ~(size_t)255;
        return p;
    };
    int*   deg  = (int*)carve((size_t)NN * 4);
    int*   rp   = (int*)carve((size_t)(NN + 1) * 4);
    int*   cur  = (int*)carve((size_t)NN * 4);
    int*   bsum = (int*)carve(512 * 4);
    int*   col  = (int*)carve((size_t)NE * 4);
    float* inv  = (float*)carve((size_t)NN * 4);
    u16*   xb   = (u16*)carve((size_t)NN * DD * 2);
    u16*   aggb = (u16*)carve((size_t)NN * DD * 2);
    u16*   Hb   = (u16*)carve((size_t)NN * DD * 2);
    u16*   Wc0  = (u16*)carve((size_t)128 * 256 * 2);
    u16*   Wc1  = (u16*)carve((size_t)128 * 256 * 2);
    float* hl2  = (float*)carve((size_t)NN * 16 * 4);
    float* agg2 = (float*)carve((size_t)NN * 16 * 4);
    (void)ws_size; (void)in_sizes; (void)n_in; (void)out_size;

    // dtype prep
    k_cast<<<(NN * 32 + 255) / 256, 256, 0, stream>>>(x, xb);
    k_prep_w<<<64, 256, 0, stream>>>(Wl0, Wr0, Wl1, Wr1, Wc0, Wc1);

    // CSR build
    hipMemsetAsync(deg, 0, (size_t)NN * 4, stream);
    k_degree<<<(NE + 255) / 256, 256, 0, stream>>>(e_dst, deg);
    k_scan1<<<NB_SCAN, 256, 0, stream>>>(deg, bsum);
    k_scan2<<<1, 128, 0, stream>>>(bsum);
    k_scan3<<<NB_SCAN, 256, 0, stream>>>(deg, bsum, rp, cur, inv);
    k_scatter<<<(NE + 255) / 256, 256, 0, stream>>>(e_src, e_dst, cur, col);

    const int nblk = (NN + 127) / 128;  // 782

    // layer 0: aggb = mean-gather(xb); Hb = relu([aggb|xb]@Wc0 + bl0)
    k_gather128b<<<NN / 16, 256, 0, stream>>>(xb, rp, col, inv, aggb);
    k_mfma_epi<<<nblk, 256, 0, stream>>>(aggb, xb, Wc0, bl0, Hb, 1);

    // layer 1 (in-place on Hb: each wave reads exactly the rows it writes)
    k_gather128b<<<NN / 16, 256, 0, stream>>>(Hb, rp, col, inv, aggb);
    k_mfma_epi<<<nblk, 256, 0, stream>>>(aggb, Hb, Wc1, bl1, Hb, 1);

    // layer 2: transform-first (16-wide gather), fused log_softmax
    k_hl2<<<(NN + 255) / 256, 256, 0, stream>>>(Hb, Wl2, hl2);
    k_gather16<<<(NN * 16 + 255) / 256, 256, 0, stream>>>(hl2, rp, col, inv, agg2);
    k_final<<<(NN + 255) / 256, 256, 0, stream>>>(Hb, agg2, Wr2, bl2, out);
}